// Round 9
// baseline (88.481 us; speedup 1.0000x reference)
//
#include <hip/hip_runtime.h>
#include <stdint.h>
#include <math.h>

#define BB 256
#define ROW 128000
#define SPLIT 16
#define CHUNK (ROW / SPLIT)        // 8000
#define THREADS 512
#define WAVES (THREADS / 64)
#define EPB (THREADS * 8)          // 4096 elems per full slab
#define GRID (BB * SPLIT)          // 4096 blocks (dynamic balancing)
#define CAP 6144                   // LDS queue entries (~37 KB LDS total)

#define SEED_THREADS 256
#define SEED_STRIDE 496            // thread t samples 8 elems at t*496

#define TF_K2 0x1BD11BF0u          // 0x1BD11BDA ^ 0 ^ 42
#define SMALL_BITS 0x00100000u     // u < 2^-12  <=>  bits < 2^20
#define MIN_L 1.4426950408889634e-10f  // 1e-10 / ln2
#define LN2 0.69314718055994530942f
// hard bound: G = -log2(L) <= -log2(MIN_L) = 32.70; 33.0 adds 0.3 slack
// covering ALL fp32 rounding in threshold/score computation.
#define GMAX 33.0f

__device__ __forceinline__ uint32_t rotl32(uint32_t x, int r) {
    return __builtin_amdgcn_alignbit(x, x, 32 - r);  // v_alignbit_b32
}

// ---- Threefry-2x32, key=(0,42), counter (0,c), out o0^o1 (bit-exact R1-R8) --
#define R1S(r)        { x0 += x1; x1 = rotl32(x1, (r)) ^ x0; }
#define RI1S(r, A, B) { x1 += (B); x0 = x0 + (A) + x1; x1 = rotl32(x1, (r)) ^ x0; }

__device__ __forceinline__ uint32_t threefry1_xor(uint32_t c) {
    uint32_t x1 = c + 42u;
    uint32_t x0 = x1;                 // round 1: x0_init = 0
    x1 = rotl32(x1, 13) ^ x0;
    R1S(15) R1S(26) R1S(6)
    RI1S(17, 42u, TF_K2 + 1u)
    R1S(29) R1S(16) R1S(24)
    RI1S(13, TF_K2, 2u)
    R1S(15) R1S(26) R1S(6)
    RI1S(17, 0u, 45u)
    R1S(29) R1S(16) R1S(24)
    RI1S(13, 42u, TF_K2 + 4u)
    R1S(15) R1S(26) R1S(6)
    return (x0 + TF_K2) ^ (x1 + 5u);
}

__device__ __forceinline__ void threefry8_xor(uint32_t c, uint32_t bits[8]) {
    uint32_t x0[8], x1[8];
#pragma unroll
    for (int j = 0; j < 8; ++j) x1[j] = c + (uint32_t)(j + 42);
#pragma unroll
    for (int j = 0; j < 8; ++j) { x0[j] = x1[j]; x1[j] = rotl32(x1[j], 13) ^ x0[j]; }

#define RND(r)                                        \
    do { _Pragma("unroll")                            \
        for (int j = 0; j < 8; ++j) {                 \
            x0[j] += x1[j];                           \
            x1[j] = rotl32(x1[j], (r)) ^ x0[j];       \
        } } while (0)
#define RNDI(r, A, B)                                 \
    do { _Pragma("unroll")                            \
        for (int j = 0; j < 8; ++j) {                 \
            x1[j] += (B);                             \
            x0[j] = x0[j] + (A) + x1[j];              \
            x1[j] = rotl32(x1[j], (r)) ^ x0[j];       \
        } } while (0)

    RND(15); RND(26); RND(6);
    RNDI(17, 42u, TF_K2 + 1u);
    RND(29); RND(16); RND(24);
    RNDI(13, TF_K2, 2u);
    RND(15); RND(26); RND(6);
    RNDI(17, 0u, 45u);
    RND(29); RND(16); RND(24);
    RNDI(13, 42u, TF_K2 + 4u);
    RND(15); RND(26); RND(6);
#undef RND
#undef RNDI

#pragma unroll
    for (int j = 0; j < 8; ++j) bits[j] = (x0[j] + TF_K2) ^ (x1[j] + 5u);
}

// L = -(E/ln2): main hw-log path, series fix-up for tiny u + 1e-10 clamp.
// Branchless — selects EXACTLY the same values as R8's gated version.
__device__ __forceinline__ float noise_negL(uint32_t bits) {
    const float uf = __uint_as_float(0x3F800000u | (bits >> 9));  // 1+u
    const float L = __builtin_amdgcn_logf(2.0f - uf);  // log2(1-u)
    const float u = uf - 1.0f;  // exact
    const float es2 = u * fmaf(u, fmaf(u, fmaf(u,
        -0.3606737602222408f, -0.4808983469629878f),
        -0.7213475204444817f), -1.4426950408889634f);
    const float es2c = fminf(es2, -MIN_L);
    return (bits < SMALL_BITS) ? es2c : L;
}

// score in log2 domain: s = x/(T*ln2) - log2(L); order == reference order
__device__ __forceinline__ float score1(float x, float invT2, uint32_t bits) {
    const float L = noise_negL(bits);
    return fmaf(x, invT2, -__builtin_amdgcn_logf(-L));
}

// order-preserving float -> uint32 map (final reduction only)
__device__ __forceinline__ uint32_t f2o(float f) {
    uint32_t u = __float_as_uint(f);
    return (u & 0x80000000u) ? ~u : (u | 0x80000000u);
}

// ---- kernel A: per-row score lower bound from a 2048-elem strided sample ---
__global__ __launch_bounds__(SEED_THREADS) void seed_kernel(
    const float* __restrict__ logits,
    const float* __restrict__ temps,
    float* __restrict__ gs) {
    const int b = blockIdx.x;
    const int t = threadIdx.x;
    const float invT2 = 1.0f / (temps[b] * LN2);
    const int off = t * SEED_STRIDE;  // 8-aligned? 496%4==0 -> float4 ok
    const float* rowp = logits + (size_t)b * ROW + off;
    const uint32_t cb = (uint32_t)b * ROW + (uint32_t)off;

    const float4 xa = *reinterpret_cast<const float4*>(rowp);
    const float4 xb = *reinterpret_cast<const float4*>(rowp + 4);
    const float xs[8] = {xa.x, xa.y, xa.z, xa.w, xb.x, xb.y, xb.z, xb.w};
    uint32_t bits[8];
    threefry8_xor(cb, bits);

    float bs = -INFINITY;
#pragma unroll
    for (int j = 0; j < 8; ++j) bs = fmaxf(bs, score1(xs[j], invT2, bits[j]));

#pragma unroll
    for (int off2 = 32; off2 >= 1; off2 >>= 1)
        bs = fmaxf(bs, __shfl_xor(bs, off2));

    __shared__ float sred[SEED_THREADS / 64];
    const int lane = t & 63, wid = t >> 6;
    if (lane == 0) sred[wid] = bs;
    __syncthreads();
    if (t == 0)
        gs[b] = fmaxf(fmaxf(sred[0], sred[1]), fmaxf(sred[2], sred[3]));
}

// ---- kernel B: scan + prune (hard bound) + dense drain ---------------------
__global__ __launch_bounds__(THREADS, 4) void sampler_kernel(
    const float* __restrict__ logits,
    const float* __restrict__ temps,
    const float* __restrict__ gs,
    unsigned long long* __restrict__ parts) {
    __shared__ int scnt;
    __shared__ unsigned short qidx[CAP];
    __shared__ float qx[CAP];
    __shared__ unsigned long long sbest[WAVES];

    const int g = blockIdx.x;
    const int b = g >> 4;            // row   (SPLIT = 16)
    const int q = g & 15;            // chunk
    const float T = temps[b];
    const float invT2 = 1.0f / (T * LN2);
    // survivor threshold: x > (gs - 33)/c = (gs - 33) * T * ln2
    const float xthr = (gs[b] - GMAX) * (T * LN2);
    const float* rowp = logits + (size_t)b * ROW + (size_t)q * CHUNK;
    const uint32_t cbase = (uint32_t)b * ROW + (uint32_t)(q * CHUNK);
    const int tid = threadIdx.x;
    const int lane = tid & 63;
    const unsigned long long lmask_lt = (1ull << lane) - 1ull;

    if (tid == 0) scnt = 0;
    __syncthreads();

    // -------- scan phase: 2 slabs, ballot-aggregated enqueue --------
    float xs0[8], xs1[8];
    {
        const int rel = tid * 8;                 // slab 0, always valid
        const float4 xa = *reinterpret_cast<const float4*>(rowp + rel);
        const float4 xb = *reinterpret_cast<const float4*>(rowp + rel + 4);
        xs0[0]=xa.x; xs0[1]=xa.y; xs0[2]=xa.z; xs0[3]=xa.w;
        xs0[4]=xb.x; xs0[5]=xb.y; xs0[6]=xb.z; xs0[7]=xb.w;
#pragma unroll
        for (int j = 0; j < 8; ++j) {
            const bool pass = xs0[j] > xthr;
            const unsigned long long mk = __ballot(pass);
            if (mk != 0ull) {
                int base = 0;
                if (lane == 0) base = atomicAdd(&scnt, __popcll(mk));
                base = __builtin_amdgcn_readfirstlane(base);
                if (pass) {
                    const int pos = base + (int)__popcll(mk & lmask_lt);
                    if (pos < CAP) {
                        qidx[pos] = (unsigned short)(rel + j);
                        qx[pos] = xs0[j];
                    }
                }
            }
        }
    }
    const int rel1 = EPB + tid * 8;              // slab 1, partial (488 thr)
    const bool in1 = rel1 < CHUNK;
    if (in1) {
        const float4 xa = *reinterpret_cast<const float4*>(rowp + rel1);
        const float4 xb = *reinterpret_cast<const float4*>(rowp + rel1 + 4);
        xs1[0]=xa.x; xs1[1]=xa.y; xs1[2]=xa.z; xs1[3]=xa.w;
        xs1[4]=xb.x; xs1[5]=xb.y; xs1[6]=xb.z; xs1[7]=xb.w;
#pragma unroll
        for (int j = 0; j < 8; ++j) {
            const bool pass = xs1[j] > xthr;
            const unsigned long long mk = __ballot(pass);
            if (mk != 0ull) {
                int base = 0;
                // first active lane does the atomic (lane 0 may be inactive
                // only in waves fully out of range, which skip entirely)
                if (lane == 0) base = atomicAdd(&scnt, __popcll(mk));
                base = __builtin_amdgcn_readfirstlane(base);
                if (pass) {
                    const int pos = base + (int)__popcll(mk & lmask_lt);
                    if (pos < CAP) {
                        qidx[pos] = (unsigned short)(rel1 + j);
                        qx[pos] = xs1[j];
                    }
                }
            }
        }
    }
    __syncthreads();

    const int total = scnt;
    float best_s = -INFINITY;
    uint32_t best_rel = 0u;

    if (total > CAP) {
        // -------- overflow (high-T rows): full evaluation, R8-style --------
        {
            const int rel = tid * 8;
            uint32_t bits[8];
            threefry8_xor(cbase + (uint32_t)rel, bits);
#pragma unroll
            for (int j = 0; j < 8; ++j) {
                const float s = score1(xs0[j], invT2, bits[j]);
                if (s > best_s) { best_s = s; best_rel = (uint32_t)(rel + j); }
            }
        }
        if (in1) {
            uint32_t bits[8];
            threefry8_xor(cbase + (uint32_t)rel1, bits);
#pragma unroll
            for (int j = 0; j < 8; ++j) {
                const float s = score1(xs1[j], invT2, bits[j]);
                if (s > best_s) { best_s = s; best_rel = (uint32_t)(rel1 + j); }
            }
        }
    } else {
        // -------- dense drain of the survivor queue --------
        for (int i = tid; i < total; i += THREADS) {
            const int rel = (int)qidx[i];
            const float x = qx[i];
            const uint32_t bits = threefry1_xor(cbase + (uint32_t)rel);
            const float s = score1(x, invT2, bits);
            if (s > best_s) { best_s = s; best_rel = (uint32_t)rel; }
        }
    }

    const uint32_t best_v = (uint32_t)(q * CHUNK) + best_rel;

    // pack (orderable(score) << 32) | ~v ; max-reduce; ties -> smallest v
    unsigned long long best =
        ((unsigned long long)f2o(best_s) << 32) | (uint32_t)(~best_v);
#pragma unroll
    for (int off = 32; off >= 1; off >>= 1) {
        const unsigned long long o = __shfl_xor(best, off);
        best = (o > best) ? o : best;
    }
    const int wid = tid >> 6;
    if (lane == 0) sbest[wid] = best;
    __syncthreads();
    if (tid == 0) {
        unsigned long long r = sbest[0];
#pragma unroll
        for (int w = 1; w < WAVES; ++w) r = (sbest[w] > r) ? sbest[w] : r;
        parts[g] = r;
    }
}

__global__ __launch_bounds__(BB) void combine_kernel(
    const unsigned long long* __restrict__ parts, int* __restrict__ out) {
    const int b = threadIdx.x;
    const unsigned long long* p = parts + b * SPLIT;
    unsigned long long r = p[0];
#pragma unroll
    for (int w = 1; w < SPLIT; ++w) r = (p[w] > r) ? p[w] : r;
    out[b] = (int)(~(uint32_t)(r & 0xFFFFFFFFull));
}

extern "C" void kernel_launch(void* const* d_in, const int* in_sizes, int n_in,
                              void* d_out, int out_size, void* d_ws, size_t ws_size,
                              hipStream_t stream) {
    const float* logits = (const float*)d_in[0];
    const float* temps = (const float*)d_in[1];
    int* out = (int*)d_out;
    // ws layout: [0,1024): gs float[256]; [1024, 1024+32768): parts u64[4096]
    float* gs = (float*)d_ws;
    unsigned long long* parts = (unsigned long long*)((char*)d_ws + 1024);

    hipLaunchKernelGGL(seed_kernel, dim3(BB), dim3(SEED_THREADS), 0, stream,
                       logits, temps, gs);
    hipLaunchKernelGGL(sampler_kernel, dim3(GRID), dim3(THREADS), 0, stream,
                       logits, temps, gs, parts);
    hipLaunchKernelGGL(combine_kernel, dim3(1), dim3(BB), 0, stream, parts, out);
}

// Round 10
// 81.131 us; speedup vs baseline: 1.0906x; 1.0906x over previous
//
#include <hip/hip_runtime.h>
#include <stdint.h>
#include <math.h>

#define BB 256
#define ROW 128000
#define SPLITM 32
#define CHUNKM (ROW / SPLITM)      // 4000
#define GRIDM (BB * SPLITM)        // 8192 blocks
#define THREADS 512
#define WAVES (THREADS / 64)

#define SEED_THREADS 256
#define SEED_STRIDE 496            // thread t samples 8 elems at t*496

#define TF_K2 0x1BD11BF0u          // 0x1BD11BDA ^ 0 ^ 42
#define SMALL_BITS 0x00100000u     // u < 2^-12  <=>  bits < 2^20
#define MIN_L 1.4426950408889634e-10f  // 1e-10 / ln2
#define LN2 0.69314718055994530942f
// G = -log2(L) <= 32.70 (clamp ceiling; u==0 elements DO occur ~4x in this
// dataset and can win rows — bound must include them). 33.0 = 0.3 slack.
#define GMAX 33.0f
#define MODE_CNT_THR 1152          // of 2048 sampled: >56% est -> full mode

__device__ __forceinline__ uint32_t rotl32(uint32_t x, int r) {
    return __builtin_amdgcn_alignbit(x, x, 32 - r);
}

// ---- Threefry-2x32, key=(0,42), ctr (0,c), out o0^o1 (bit-exact R1-R9) ----
#define R1S(r)        { x0 += x1; x1 = rotl32(x1, (r)) ^ x0; }
#define RI1S(r, A, B) { x1 += (B); x0 = x0 + (A) + x1; x1 = rotl32(x1, (r)) ^ x0; }

__device__ __forceinline__ uint32_t threefry1_xor(uint32_t c) {
    uint32_t x1 = c + 42u;
    uint32_t x0 = x1;                 // round 1: x0_init = 0
    x1 = rotl32(x1, 13) ^ x0;
    R1S(15) R1S(26) R1S(6)
    RI1S(17, 42u, TF_K2 + 1u)
    R1S(29) R1S(16) R1S(24)
    RI1S(13, TF_K2, 2u)
    R1S(15) R1S(26) R1S(6)
    RI1S(17, 0u, 45u)
    R1S(29) R1S(16) R1S(24)
    RI1S(13, 42u, TF_K2 + 4u)
    R1S(15) R1S(26) R1S(6)
    return (x0 + TF_K2) ^ (x1 + 5u);
}

__device__ __forceinline__ void threefry8_xor(uint32_t c, uint32_t bits[8]) {
    uint32_t x0[8], x1[8];
#pragma unroll
    for (int j = 0; j < 8; ++j) x1[j] = c + (uint32_t)(j + 42);
#pragma unroll
    for (int j = 0; j < 8; ++j) { x0[j] = x1[j]; x1[j] = rotl32(x1[j], 13) ^ x0[j]; }

#define RND(r)                                        \
    do { _Pragma("unroll")                            \
        for (int j = 0; j < 8; ++j) {                 \
            x0[j] += x1[j];                           \
            x1[j] = rotl32(x1[j], (r)) ^ x0[j];       \
        } } while (0)
#define RNDI(r, A, B)                                 \
    do { _Pragma("unroll")                            \
        for (int j = 0; j < 8; ++j) {                 \
            x1[j] += (B);                             \
            x0[j] = x0[j] + (A) + x1[j];              \
            x1[j] = rotl32(x1[j], (r)) ^ x0[j];       \
        } } while (0)

    RND(15); RND(26); RND(6);
    RNDI(17, 42u, TF_K2 + 1u);
    RND(29); RND(16); RND(24);
    RNDI(13, TF_K2, 2u);
    RND(15); RND(26); RND(6);
    RNDI(17, 0u, 45u);
    RND(29); RND(16); RND(24);
    RNDI(13, 42u, TF_K2 + 4u);
    RND(15); RND(26); RND(6);
#undef RND
#undef RNDI

#pragma unroll
    for (int j = 0; j < 8; ++j) bits[j] = (x0[j] + TF_K2) ^ (x1[j] + 5u);
}

// L = -(E/ln2): hw-log main path, series+clamp for tiny u. Branchless;
// selects bit-identical values to the gated version.
__device__ __forceinline__ float noise_negL(uint32_t bits) {
    const float uf = __uint_as_float(0x3F800000u | (bits >> 9));  // 1+u
    const float L = __builtin_amdgcn_logf(2.0f - uf);  // log2(1-u)
    const float u = uf - 1.0f;  // exact
    const float es2 = u * fmaf(u, fmaf(u, fmaf(u,
        -0.3606737602222408f, -0.4808983469629878f),
        -0.7213475204444817f), -1.4426950408889634f);
    const float es2c = fminf(es2, -MIN_L);
    return (bits < SMALL_BITS) ? es2c : L;
}

// score in log2 domain: s = x/(T*ln2) - log2(L); order == reference order
__device__ __forceinline__ float score1(float x, float invT2, uint32_t bits) {
    const float L = noise_negL(bits);
    return fmaf(x, invT2, -__builtin_amdgcn_logf(-L));
}

// order-preserving float -> uint32 map (final reduction only)
__device__ __forceinline__ uint32_t f2o(float f) {
    uint32_t u = __float_as_uint(f);
    return (u & 0x80000000u) ? ~u : (u | 0x80000000u);
}

// ---- K1: per-chunk argmax of x (memory-bound) ------------------------------
__global__ __launch_bounds__(THREADS) void chunkmax_kernel(
    const float* __restrict__ logits, float* __restrict__ cmx,
    uint32_t* __restrict__ cmi) {
    const int g = blockIdx.x;
    const int b = g >> 5, q = g & 31;
    const float* rowp = logits + (size_t)b * ROW + (size_t)q * CHUNKM;
    const int tid = threadIdx.x;
    const int rel = tid * 8;

    float mx = -INFINITY;
    uint32_t mi = 0u;
    if (rel < CHUNKM) {
        const float4 xa = *reinterpret_cast<const float4*>(rowp + rel);
        const float4 xb = *reinterpret_cast<const float4*>(rowp + rel + 4);
        const float xs[8] = {xa.x, xa.y, xa.z, xa.w, xb.x, xb.y, xb.z, xb.w};
#pragma unroll
        for (int j = 0; j < 8; ++j)
            if (xs[j] > mx) { mx = xs[j]; mi = (uint32_t)(rel + j); }
    }
#pragma unroll
    for (int off = 32; off >= 1; off >>= 1) {
        const float ox = __shfl_xor(mx, off);
        const uint32_t oi = __shfl_xor(mi, off);
        if (ox > mx) { mx = ox; mi = oi; }
    }
    __shared__ float smx[WAVES];
    __shared__ uint32_t smi[WAVES];
    const int lane = tid & 63, wid = tid >> 6;
    if (lane == 0) { smx[wid] = mx; smi[wid] = mi; }
    __syncthreads();
    if (tid == 0) {
        mx = smx[0]; mi = smi[0];
#pragma unroll
        for (int w = 1; w < WAVES; ++w)
            if (smx[w] > mx) { mx = smx[w]; mi = smi[w]; }
        cmx[g] = mx;
        cmi[g] = (uint32_t)(q * CHUNKM) + mi;  // row-relative index
    }
}

// ---- K2: per-row gs (score lower bound) + mode flag ------------------------
__global__ __launch_bounds__(SEED_THREADS) void rowseed_kernel(
    const float* __restrict__ logits, const float* __restrict__ temps,
    const float* __restrict__ cmx, const uint32_t* __restrict__ cmi,
    float* __restrict__ gs, int* __restrict__ mode) {
    const int b = blockIdx.x;
    const int t = threadIdx.x;
    const float T = temps[b];
    const float invT2 = 1.0f / (T * LN2);
    const int off = t * SEED_STRIDE;
    const float* rowp = logits + (size_t)b * ROW + off;
    const uint32_t cb = (uint32_t)b * ROW + (uint32_t)off;

    const float4 xa = *reinterpret_cast<const float4*>(rowp);
    const float4 xb = *reinterpret_cast<const float4*>(rowp + 4);
    const float xs[8] = {xa.x, xa.y, xa.z, xa.w, xb.x, xb.y, xb.z, xb.w};
    uint32_t bits[8];
    threefry8_xor(cb, bits);

    float bs = -INFINITY;
#pragma unroll
    for (int j = 0; j < 8; ++j) bs = fmaxf(bs, score1(xs[j], invT2, bits[j]));

    // exact scores at the 32 chunk-argmax elements (covers the row x-max)
    if (t < SPLITM) {
        const uint32_t idx = cmi[b * SPLITM + t];
        const float xm = cmx[b * SPLITM + t];
        bs = fmaxf(bs, score1(xm, invT2,
                              threefry1_xor((uint32_t)b * ROW + idx)));
    }

#pragma unroll
    for (int o = 32; o >= 1; o >>= 1) bs = fmaxf(bs, __shfl_xor(bs, o));
    __shared__ float sred[SEED_THREADS / 64];
    __shared__ int scr[SEED_THREADS / 64];
    const int lane = t & 63, wid = t >> 6;
    if (lane == 0) sred[wid] = bs;
    __syncthreads();
    const float gsv = fmaxf(fmaxf(sred[0], sred[1]), fmaxf(sred[2], sred[3]));

    // survivor-fraction estimate on the sample -> mode flag
    const float xthr = (gsv - GMAX) * (T * LN2);
    int c = 0;
#pragma unroll
    for (int j = 0; j < 8; ++j) c += (xs[j] > xthr) ? 1 : 0;
#pragma unroll
    for (int o = 32; o >= 1; o >>= 1) c += __shfl_xor(c, o);
    if (lane == 0) scr[wid] = c;
    __syncthreads();
    if (t == 0) {
        const int tot = scr[0] + scr[1] + scr[2] + scr[3];
        gs[b] = gsv;
        mode[b] = (tot > MODE_CNT_THR) ? 1 : 0;
    }
}

// ---- K3: main — full eval (high T) or scan+prune+drain (low/mid T) ---------
__global__ __launch_bounds__(THREADS, 4) void sampler_kernel(
    const float* __restrict__ logits, const float* __restrict__ temps,
    const float* __restrict__ gs, const int* __restrict__ mode,
    unsigned long long* __restrict__ parts) {
    __shared__ int scnt;
    __shared__ unsigned short qidx[CHUNKM];   // CAP == CHUNKM: cannot overflow
    __shared__ unsigned long long sbest[WAVES];

    const int g = blockIdx.x;
    const int b = g >> 5, q = g & 31;
    const float T = temps[b];
    const float invT2 = 1.0f / (T * LN2);
    const float xthr = (gs[b] - GMAX) * (T * LN2);
    const float* rowp = logits + (size_t)b * ROW + (size_t)q * CHUNKM;
    const uint32_t cbase = (uint32_t)b * ROW + (uint32_t)(q * CHUNKM);
    const int tid = threadIdx.x;
    const int lane = tid & 63;
    const unsigned long long lmask_lt = (1ull << lane) - 1ull;

    if (tid == 0) scnt = 0;
    __syncthreads();

    const int rel = tid * 8;
    const bool act = rel < CHUNKM;            // 500 of 512 threads
    float xs[8];
    if (act) {
        const float4 xa = *reinterpret_cast<const float4*>(rowp + rel);
        const float4 xb = *reinterpret_cast<const float4*>(rowp + rel + 4);
        xs[0]=xa.x; xs[1]=xa.y; xs[2]=xa.z; xs[3]=xa.w;
        xs[4]=xb.x; xs[5]=xb.y; xs[6]=xb.z; xs[7]=xb.w;
    }

    float best_s = -INFINITY;
    uint32_t best_rel = 0u;

    if (mode[b]) {
        // -------- full evaluation (noise-dominated rows) --------
        if (act) {
            uint32_t bits[8];
            threefry8_xor(cbase + (uint32_t)rel, bits);
            float L8[8];
#pragma unroll
            for (int j = 0; j < 8; ++j) {
                const float uf = __uint_as_float(0x3F800000u | (bits[j] >> 9));
                L8[j] = __builtin_amdgcn_logf(2.0f - uf);
            }
            const uint32_t b01 = min(min(bits[0], bits[1]), bits[2]);
            const uint32_t b34 = min(min(bits[3], bits[4]), bits[5]);
            const uint32_t b67 = min(bits[6], bits[7]);
            if (__any(min(min(b01, b34), b67) < SMALL_BITS)) {
#pragma unroll
                for (int j = 0; j < 8; ++j) {
                    const float u = __uint_as_float(0x3F800000u |
                                    (bits[j] >> 9)) - 1.0f;
                    const float es2 = u * fmaf(u, fmaf(u, fmaf(u,
                        -0.3606737602222408f, -0.4808983469629878f),
                        -0.7213475204444817f), -1.4426950408889634f);
                    const float es2c = fminf(es2, -MIN_L);
                    L8[j] = (bits[j] < SMALL_BITS) ? es2c : L8[j];
                }
            }
#pragma unroll
            for (int j = 0; j < 8; ++j) {
                const float s = fmaf(xs[j], invT2,
                                     -__builtin_amdgcn_logf(-L8[j]));
                if (s > best_s) { best_s = s; best_rel = (uint32_t)(rel + j); }
            }
        }
    } else {
        // -------- scan + prune (hard clamp bound) + drain --------
        if (act) {
#pragma unroll
            for (int j = 0; j < 8; ++j) {
                const bool pass = xs[j] > xthr;
                const unsigned long long mk = __ballot(pass);
                if (mk != 0ull) {
                    int base = 0;
                    if (lane == 0) base = atomicAdd(&scnt, __popcll(mk));
                    base = __builtin_amdgcn_readfirstlane(base);
                    if (pass) {
                        const int pos = base + (int)__popcll(mk & lmask_lt);
                        qidx[pos] = (unsigned short)(rel + j);
                    }
                }
            }
        }
        __syncthreads();
        const int total = scnt;
        for (int i = tid; i < total; i += THREADS) {
            const int r2 = (int)qidx[i];
            const float x = rowp[r2];   // L1-hot: this block just read it
            const float s = score1(x, invT2, threefry1_xor(cbase + (uint32_t)r2));
            if (s > best_s) { best_s = s; best_rel = (uint32_t)r2; }
        }
    }

    const uint32_t best_v = (uint32_t)(q * CHUNKM) + best_rel;
    unsigned long long best =
        ((unsigned long long)f2o(best_s) << 32) | (uint32_t)(~best_v);
#pragma unroll
    for (int off = 32; off >= 1; off >>= 1) {
        const unsigned long long o = __shfl_xor(best, off);
        best = (o > best) ? o : best;
    }
    const int wid = tid >> 6;
    if (lane == 0) sbest[wid] = best;
    __syncthreads();
    if (tid == 0) {
        unsigned long long r = sbest[0];
#pragma unroll
        for (int w = 1; w < WAVES; ++w) r = (sbest[w] > r) ? sbest[w] : r;
        parts[g] = r;
    }
}

// ---- K4: combine 32 partials per row ---------------------------------------
__global__ __launch_bounds__(BB) void combine_kernel(
    const unsigned long long* __restrict__ parts, int* __restrict__ out) {
    const int b = threadIdx.x;
    const unsigned long long* p = parts + b * SPLITM;
    unsigned long long r = p[0];
#pragma unroll
    for (int w = 1; w < SPLITM; ++w) r = (p[w] > r) ? p[w] : r;
    out[b] = (int)(~(uint32_t)(r & 0xFFFFFFFFull));
}

extern "C" void kernel_launch(void* const* d_in, const int* in_sizes, int n_in,
                              void* d_out, int out_size, void* d_ws, size_t ws_size,
                              hipStream_t stream) {
    const float* logits = (const float*)d_in[0];
    const float* temps = (const float*)d_in[1];
    int* out = (int*)d_out;
    // ws layout (133 KB):
    float* cmx = (float*)d_ws;                                   // 32 KB
    uint32_t* cmi = (uint32_t*)((char*)d_ws + 32768);            // 32 KB
    float* gs = (float*)((char*)d_ws + 65536);                   // 1 KB
    int* mode = (int*)((char*)d_ws + 66560);                     // 1 KB
    unsigned long long* parts =
        (unsigned long long*)((char*)d_ws + 67584);              // 64 KB

    hipLaunchKernelGGL(chunkmax_kernel, dim3(GRIDM), dim3(THREADS), 0, stream,
                       logits, cmx, cmi);
    hipLaunchKernelGGL(rowseed_kernel, dim3(BB), dim3(SEED_THREADS), 0, stream,
                       logits, temps, cmx, cmi, gs, mode);
    hipLaunchKernelGGL(sampler_kernel, dim3(GRIDM), dim3(THREADS), 0, stream,
                       logits, temps, gs, mode, parts);
    hipLaunchKernelGGL(combine_kernel, dim3(1), dim3(BB), 0, stream, parts, out);
}

// Round 11
// 77.447 us; speedup vs baseline: 1.1425x; 1.0476x over previous
//
#include <hip/hip_runtime.h>
#include <stdint.h>
#include <math.h>

#define BB 256
#define ROW 128000
#define SPLITM 32
#define CHUNKM (ROW / SPLITM)      // 4000
#define GRIDM (BB * SPLITM)        // 8192 blocks
#define THREADS 512
#define WAVES (THREADS / 64)

#define SEED_THREADS 256
#define SEED_STRIDE 496            // thread t samples 8 elems at t*496

#define TF_K2 0x1BD11BF0u          // 0x1BD11BDA ^ 0 ^ 42
#define SMALL_BITS 0x00100000u     // u < 2^-12  <=>  bits < 2^20
#define MIN_L 1.4426950408889634e-10f  // 1e-10 / ln2
#define LN2 0.69314718055994530942f
// G = -log2(L) <= 32.70 (clamp ceiling; u==0 elements occur ~4x in this
// dataset and can win rows — bound must include them). 33.0 = 0.3 slack.
// NOTE (audited R10): tightening to the u>0 ceiling (22.47) is NOT valid
// without threefry-checking the band — no cheaper u==0 test exists.
#define GMAX 33.0f
// mode: prune wins while survivor s < ~0.77 (15 + s*95 vs 88 insts/elem);
// estimate uses loose gs0 (biased high) -> 0.70*2048 is safe.
#define MODE_CNT_THR 1434

__device__ __forceinline__ uint32_t rotl32(uint32_t x, int r) {
    return __builtin_amdgcn_alignbit(x, x, 32 - r);
}

// ---- Threefry-2x32, key=(0,42), ctr (0,c), out o0^o1 (bit-exact R1-R10) ---
#define R1S(r)        { x0 += x1; x1 = rotl32(x1, (r)) ^ x0; }
#define RI1S(r, A, B) { x1 += (B); x0 = x0 + (A) + x1; x1 = rotl32(x1, (r)) ^ x0; }

__device__ __forceinline__ uint32_t threefry1_xor(uint32_t c) {
    uint32_t x1 = c + 42u;
    uint32_t x0 = x1;                 // round 1: x0_init = 0
    x1 = rotl32(x1, 13) ^ x0;
    R1S(15) R1S(26) R1S(6)
    RI1S(17, 42u, TF_K2 + 1u)
    R1S(29) R1S(16) R1S(24)
    RI1S(13, TF_K2, 2u)
    R1S(15) R1S(26) R1S(6)
    RI1S(17, 0u, 45u)
    R1S(29) R1S(16) R1S(24)
    RI1S(13, 42u, TF_K2 + 4u)
    R1S(15) R1S(26) R1S(6)
    return (x0 + TF_K2) ^ (x1 + 5u);
}

__device__ __forceinline__ void threefry8_xor(uint32_t c, uint32_t bits[8]) {
    uint32_t x0[8], x1[8];
#pragma unroll
    for (int j = 0; j < 8; ++j) x1[j] = c + (uint32_t)(j + 42);
#pragma unroll
    for (int j = 0; j < 8; ++j) { x0[j] = x1[j]; x1[j] = rotl32(x1[j], 13) ^ x0[j]; }

#define RND(r)                                        \
    do { _Pragma("unroll")                            \
        for (int j = 0; j < 8; ++j) {                 \
            x0[j] += x1[j];                           \
            x1[j] = rotl32(x1[j], (r)) ^ x0[j];       \
        } } while (0)
#define RNDI(r, A, B)                                 \
    do { _Pragma("unroll")                            \
        for (int j = 0; j < 8; ++j) {                 \
            x1[j] += (B);                             \
            x0[j] = x0[j] + (A) + x1[j];              \
            x1[j] = rotl32(x1[j], (r)) ^ x0[j];       \
        } } while (0)

    RND(15); RND(26); RND(6);
    RNDI(17, 42u, TF_K2 + 1u);
    RND(29); RND(16); RND(24);
    RNDI(13, TF_K2, 2u);
    RND(15); RND(26); RND(6);
    RNDI(17, 0u, 45u);
    RND(29); RND(16); RND(24);
    RNDI(13, 42u, TF_K2 + 4u);
    RND(15); RND(26); RND(6);
#undef RND
#undef RNDI

#pragma unroll
    for (int j = 0; j < 8; ++j) bits[j] = (x0[j] + TF_K2) ^ (x1[j] + 5u);
}

// L = -(E/ln2): hw-log main path, series+clamp for tiny u. Branchless;
// selects bit-identical values to the gated version.
__device__ __forceinline__ float noise_negL(uint32_t bits) {
    const float uf = __uint_as_float(0x3F800000u | (bits >> 9));  // 1+u
    const float L = __builtin_amdgcn_logf(2.0f - uf);  // log2(1-u)
    const float u = uf - 1.0f;  // exact
    const float es2 = u * fmaf(u, fmaf(u, fmaf(u,
        -0.3606737602222408f, -0.4808983469629878f),
        -0.7213475204444817f), -1.4426950408889634f);
    const float es2c = fminf(es2, -MIN_L);
    return (bits < SMALL_BITS) ? es2c : L;
}

// score in log2 domain: s = x/(T*ln2) - log2(L); order == reference order
__device__ __forceinline__ float score1(float x, float invT2, uint32_t bits) {
    const float L = noise_negL(bits);
    return fmaf(x, invT2, -__builtin_amdgcn_logf(-L));
}

// order-preserving float -> uint32 map (final reduction only)
__device__ __forceinline__ uint32_t f2o(float f) {
    uint32_t u = __float_as_uint(f);
    return (u & 0x80000000u) ? ~u : (u | 0x80000000u);
}

// ---- K0: per-row sampled score bound gs0 + mode flag -----------------------
__global__ __launch_bounds__(SEED_THREADS) void premode_kernel(
    const float* __restrict__ logits, const float* __restrict__ temps,
    float* __restrict__ gs0, int* __restrict__ mode) {
    const int b = blockIdx.x;
    const int t = threadIdx.x;
    const float T = temps[b];
    const float invT2 = 1.0f / (T * LN2);
    const int off = t * SEED_STRIDE;
    const float* rowp = logits + (size_t)b * ROW + off;
    const uint32_t cb = (uint32_t)b * ROW + (uint32_t)off;

    const float4 xa = *reinterpret_cast<const float4*>(rowp);
    const float4 xb = *reinterpret_cast<const float4*>(rowp + 4);
    const float xs[8] = {xa.x, xa.y, xa.z, xa.w, xb.x, xb.y, xb.z, xb.w};
    uint32_t bits[8];
    threefry8_xor(cb, bits);

    float bs = -INFINITY;
#pragma unroll
    for (int j = 0; j < 8; ++j) bs = fmaxf(bs, score1(xs[j], invT2, bits[j]));

#pragma unroll
    for (int o = 32; o >= 1; o >>= 1) bs = fmaxf(bs, __shfl_xor(bs, o));
    __shared__ float sred[SEED_THREADS / 64];
    __shared__ int scr[SEED_THREADS / 64];
    const int lane = t & 63, wid = t >> 6;
    if (lane == 0) sred[wid] = bs;
    __syncthreads();
    const float gsv = fmaxf(fmaxf(sred[0], sred[1]), fmaxf(sred[2], sred[3]));

    // survivor-fraction estimate on the sample -> mode flag
    const float xthr = (gsv - GMAX) * (T * LN2);
    int c = 0;
#pragma unroll
    for (int j = 0; j < 8; ++j) c += (xs[j] > xthr) ? 1 : 0;
#pragma unroll
    for (int o = 32; o >= 1; o >>= 1) c += __shfl_xor(c, o);
    if (lane == 0) scr[wid] = c;
    __syncthreads();
    if (t == 0) {
        const int tot = scr[0] + scr[1] + scr[2] + scr[3];
        gs0[b] = gsv;
        mode[b] = (tot > MODE_CNT_THR) ? 1 : 0;
    }
}

// ---- K1: per-chunk argmax of x — PRUNE-MODE ROWS ONLY ----------------------
__global__ __launch_bounds__(THREADS) void chunkmax_kernel(
    const float* __restrict__ logits, const int* __restrict__ mode,
    float* __restrict__ cmx, uint32_t* __restrict__ cmi) {
    const int g = blockIdx.x;
    const int b = g >> 5, q = g & 31;
    if (mode[b]) return;               // full-eval rows don't need gs
    const float* rowp = logits + (size_t)b * ROW + (size_t)q * CHUNKM;
    const int tid = threadIdx.x;
    const int rel = tid * 8;

    float mx = -INFINITY;
    uint32_t mi = 0u;
    if (rel < CHUNKM) {
        const float4 xa = *reinterpret_cast<const float4*>(rowp + rel);
        const float4 xb = *reinterpret_cast<const float4*>(rowp + rel + 4);
        const float xs[8] = {xa.x, xa.y, xa.z, xa.w, xb.x, xb.y, xb.z, xb.w};
#pragma unroll
        for (int j = 0; j < 8; ++j)
            if (xs[j] > mx) { mx = xs[j]; mi = (uint32_t)(rel + j); }
    }
#pragma unroll
    for (int off = 32; off >= 1; off >>= 1) {
        const float ox = __shfl_xor(mx, off);
        const uint32_t oi = __shfl_xor(mi, off);
        if (ox > mx) { mx = ox; mi = oi; }
    }
    __shared__ float smx[WAVES];
    __shared__ uint32_t smi[WAVES];
    const int lane = tid & 63, wid = tid >> 6;
    if (lane == 0) { smx[wid] = mx; smi[wid] = mi; }
    __syncthreads();
    if (tid == 0) {
        mx = smx[0]; mi = smi[0];
#pragma unroll
        for (int w = 1; w < WAVES; ++w)
            if (smx[w] > mx) { mx = smx[w]; mi = smi[w]; }
        cmx[g] = mx;
        cmi[g] = (uint32_t)(q * CHUNKM) + mi;  // row-relative index
    }
}

// ---- K3: main — full eval (high T) or inline-gs scan+prune+drain -----------
__global__ __launch_bounds__(THREADS, 4) void sampler_kernel(
    const float* __restrict__ logits, const float* __restrict__ temps,
    const float* __restrict__ gs0, const int* __restrict__ mode,
    const float* __restrict__ cmx, const uint32_t* __restrict__ cmi,
    unsigned long long* __restrict__ parts) {
    __shared__ int scnt;
    __shared__ float s_xthr;
    __shared__ unsigned short qidx[CHUNKM];   // CAP == CHUNKM: no overflow
    __shared__ unsigned long long sbest[WAVES];

    const int g = blockIdx.x;
    const int b = g >> 5, q = g & 31;
    const int md = mode[b];
    const float T = temps[b];
    const float invT2 = 1.0f / (T * LN2);
    const float* rowp = logits + (size_t)b * ROW + (size_t)q * CHUNKM;
    const uint32_t cbase = (uint32_t)b * ROW + (uint32_t)(q * CHUNKM);
    const int tid = threadIdx.x;
    const int lane = tid & 63;
    const unsigned long long lmask_lt = (1ull << lane) - 1ull;

    // prune rows: refine gs inline from the 32 chunk-argmax candidates
    // (32 threefry1 per block — negligible) + the sampled gs0.
    if (!md) {
        if (tid == 0) scnt = 0;
        if (tid < SPLITM) {
            const uint32_t idx = cmi[b * SPLITM + tid];
            const float xm = cmx[b * SPLITM + tid];
            float cs = score1(xm, invT2,
                              threefry1_xor((uint32_t)b * ROW + idx));
            cs = fmaxf(cs, gs0[b]);
#pragma unroll
            for (int o = 16; o >= 1; o >>= 1)
                cs = fmaxf(cs, __shfl_xor(cs, o));  // lanes 0..31 closed set
            if (tid == 0) s_xthr = (cs - GMAX) * (T * LN2);
        }
        __syncthreads();
    }

    const int rel = tid * 8;
    const bool act = rel < CHUNKM;            // 500 of 512 threads
    float xs[8];
    if (act) {
        const float4 xa = *reinterpret_cast<const float4*>(rowp + rel);
        const float4 xb = *reinterpret_cast<const float4*>(rowp + rel + 4);
        xs[0]=xa.x; xs[1]=xa.y; xs[2]=xa.z; xs[3]=xa.w;
        xs[4]=xb.x; xs[5]=xb.y; xs[6]=xb.z; xs[7]=xb.w;
    }

    float best_s = -INFINITY;
    uint32_t best_rel = 0u;

    if (md) {
        // -------- full evaluation (noise-dominated rows) --------
        if (act) {
            uint32_t bits[8];
            threefry8_xor(cbase + (uint32_t)rel, bits);
            float L8[8];
#pragma unroll
            for (int j = 0; j < 8; ++j) {
                const float uf = __uint_as_float(0x3F800000u | (bits[j] >> 9));
                L8[j] = __builtin_amdgcn_logf(2.0f - uf);
            }
            const uint32_t b01 = min(min(bits[0], bits[1]), bits[2]);
            const uint32_t b34 = min(min(bits[3], bits[4]), bits[5]);
            const uint32_t b67 = min(bits[6], bits[7]);
            if (__any(min(min(b01, b34), b67) < SMALL_BITS)) {
#pragma unroll
                for (int j = 0; j < 8; ++j) {
                    const float u = __uint_as_float(0x3F800000u |
                                    (bits[j] >> 9)) - 1.0f;
                    const float es2 = u * fmaf(u, fmaf(u, fmaf(u,
                        -0.3606737602222408f, -0.4808983469629878f),
                        -0.7213475204444817f), -1.4426950408889634f);
                    const float es2c = fminf(es2, -MIN_L);
                    L8[j] = (bits[j] < SMALL_BITS) ? es2c : L8[j];
                }
            }
#pragma unroll
            for (int j = 0; j < 8; ++j) {
                const float s = fmaf(xs[j], invT2,
                                     -__builtin_amdgcn_logf(-L8[j]));
                if (s > best_s) { best_s = s; best_rel = (uint32_t)(rel + j); }
            }
        }
    } else {
        // -------- scan + prune (hard clamp bound) + drain --------
        const float xthr = s_xthr;
        if (act) {
#pragma unroll
            for (int j = 0; j < 8; ++j) {
                const bool pass = xs[j] > xthr;
                const unsigned long long mk = __ballot(pass);
                if (mk != 0ull) {
                    int base = 0;
                    if (lane == 0) base = atomicAdd(&scnt, __popcll(mk));
                    base = __builtin_amdgcn_readfirstlane(base);
                    if (pass) {
                        const int pos = base + (int)__popcll(mk & lmask_lt);
                        qidx[pos] = (unsigned short)(rel + j);
                    }
                }
            }
        }
        __syncthreads();
        const int total = scnt;
        for (int i = tid; i < total; i += THREADS) {
            const int r2 = (int)qidx[i];
            const float x = rowp[r2];   // L1/L2-hot: block just read it
            const float s = score1(x, invT2, threefry1_xor(cbase + (uint32_t)r2));
            if (s > best_s) { best_s = s; best_rel = (uint32_t)r2; }
        }
    }

    const uint32_t best_v = (uint32_t)(q * CHUNKM) + best_rel;
    unsigned long long best =
        ((unsigned long long)f2o(best_s) << 32) | (uint32_t)(~best_v);
#pragma unroll
    for (int off = 32; off >= 1; off >>= 1) {
        const unsigned long long o = __shfl_xor(best, off);
        best = (o > best) ? o : best;
    }
    const int wid = tid >> 6;
    if (lane == 0) sbest[wid] = best;
    __syncthreads();
    if (tid == 0) {
        unsigned long long r = sbest[0];
#pragma unroll
        for (int w = 1; w < WAVES; ++w) r = (sbest[w] > r) ? sbest[w] : r;
        parts[g] = r;
    }
}

// ---- K4: combine 32 partials per row ---------------------------------------
__global__ __launch_bounds__(BB) void combine_kernel(
    const unsigned long long* __restrict__ parts, int* __restrict__ out) {
    const int b = threadIdx.x;
    const unsigned long long* p = parts + b * SPLITM;
    unsigned long long r = p[0];
#pragma unroll
    for (int w = 1; w < SPLITM; ++w) r = (p[w] > r) ? p[w] : r;
    out[b] = (int)(~(uint32_t)(r & 0xFFFFFFFFull));
}

extern "C" void kernel_launch(void* const* d_in, const int* in_sizes, int n_in,
                              void* d_out, int out_size, void* d_ws, size_t ws_size,
                              hipStream_t stream) {
    const float* logits = (const float*)d_in[0];
    const float* temps = (const float*)d_in[1];
    int* out = (int*)d_out;
    // ws layout (133 KB):
    float* cmx = (float*)d_ws;                                   // 32 KB
    uint32_t* cmi = (uint32_t*)((char*)d_ws + 32768);            // 32 KB
    float* gs0 = (float*)((char*)d_ws + 65536);                  // 1 KB
    int* mode = (int*)((char*)d_ws + 66560);                     // 1 KB
    unsigned long long* parts =
        (unsigned long long*)((char*)d_ws + 67584);              // 64 KB

    hipLaunchKernelGGL(premode_kernel, dim3(BB), dim3(SEED_THREADS), 0, stream,
                       logits, temps, gs0, mode);
    hipLaunchKernelGGL(chunkmax_kernel, dim3(GRIDM), dim3(THREADS), 0, stream,
                       logits, mode, cmx, cmi);
    hipLaunchKernelGGL(sampler_kernel, dim3(GRIDM), dim3(THREADS), 0, stream,
                       logits, temps, gs0, mode, cmx, cmi, parts);
    hipLaunchKernelGGL(combine_kernel, dim3(1), dim3(BB), 0, stream, parts, out);
}